// Round 18
// baseline (306.556 us; speedup 1.0000x reference)
//
#include <hip/hip_runtime.h>
#include <stdint.h>

// Problem constants (PureSAGEConv): N=50000, C_in=512, C_out=512, E=800000
#define CI 512
#define CO 512
#define CPAD 8   // counter padding stride (ints): 4 counters per 128B line

typedef __attribute__((ext_vector_type(4))) float f32x4;
typedef __attribute__((ext_vector_type(8))) __bf16 bf16x8;

#define AS1 __attribute__((address_space(1)))
#define AS3 __attribute__((address_space(3)))

__device__ __forceinline__ unsigned short f2bf_bits(float f) {
  union { float f; unsigned int u; } v; v.f = f;
  unsigned int u = v.u;
  unsigned int lsb = (u >> 16) & 1u;
  u += 0x7fffu + lsb;                 // round-to-nearest-even
  return (unsigned short)(u >> 16);
}

// ---- stage 0: degree histogram (blocks first) + W convert ----
__global__ void k_prep0(const int* __restrict__ dst, int* __restrict__ cnt, int E,
                        const float* __restrict__ W, unsigned short* __restrict__ Wb,
                        int nw4, int bd) {
  const int b = blockIdx.x;
  if (b < bd) {
    int e = b * 256 + threadIdx.x;
    if (e < E) atomicAdd(&cnt[dst[e] * CPAD], 1);
  } else {
    int i = (b - bd) * 256 + threadIdx.x;
    if (i < nw4) {
      float4 v = reinterpret_cast<const float4*>(W)[i];
      ushort4 o;
      o.x = f2bf_bits(v.x); o.y = f2bf_bits(v.y);
      o.z = f2bf_bits(v.z); o.w = f2bf_bits(v.w);
      reinterpret_cast<ushort4*>(Wb)[i] = o;
    }
  }
}

// ---- per-256-node block sums of (padded) degree counters ----
__global__ void k_bsum(const int* __restrict__ cnt, int* __restrict__ bsum, int n) {
  int t = threadIdx.x;
  int i = blockIdx.x * 256 + t;
  int v = (i < n) ? cnt[(size_t)i * CPAD] : 0;
  #pragma unroll
  for (int off = 32; off; off >>= 1) v += __shfl_down(v, off, 64);
  __shared__ int ws[4];
  if ((t & 63) == 0) ws[t >> 6] = v;
  __syncthreads();
  if (t == 0) bsum[blockIdx.x] = ws[0] + ws[1] + ws[2] + ws[3];
}

// ---- merged scan (also zeroes fill cursors -> memset shrinks 3x) ----
__global__ void k_scanf(const int* __restrict__ cnt, const int* __restrict__ bsum,
                        int* __restrict__ rowptr,
                        int* __restrict__ curA, int* __restrict__ curB,
                        int n, int nb) {
  int t = threadIdx.x, lane = t & 63, w = t >> 6;
  __shared__ int ws1[4], ws2[4], sboff;

  int v0 = (t < nb) ? bsum[t] : 0;
  int s0 = v0;
  #pragma unroll
  for (int off = 1; off < 64; off <<= 1) {
    int u = __shfl_up(s0, off, 64);
    if (lane >= off) s0 += u;
  }
  if (lane == 63) ws1[w] = s0;
  __syncthreads();
  if (t == blockIdx.x) {
    int add0 = 0;
    for (int j = 0; j < w; ++j) add0 += ws1[j];
    sboff = s0 + add0 - v0;            // exclusive offset for this block
  }
  __syncthreads();

  int i = blockIdx.x * 256 + t;
  int v = (i < n) ? cnt[(size_t)i * CPAD] : 0;
  int s = v;
  #pragma unroll
  for (int off = 1; off < 64; off <<= 1) {
    int u = __shfl_up(s, off, 64);
    if (lane >= off) s += u;
  }
  if (lane == 63) ws2[w] = s;
  __syncthreads();
  int add = sboff;
  for (int j = 0; j < w; ++j) add += ws2[j];
  if (i < n) {
    rowptr[i + 1] = s + add;
    curA[(size_t)i * CPAD] = 0;        // zero cursors here (fillx runs next)
    curB[(size_t)i * CPAD] = 0;
  }
  if (i == 0) rowptr[0] = 0;
}

// ---- merged: CSR fill (latency-bound, blocks FIRST) + x->bf16 convert
// (BW-bound, floods in behind). ----
__global__ void k_fillx(const int* __restrict__ src, const int* __restrict__ dst,
                        const int* __restrict__ rowptr,
                        int* __restrict__ curA, int* __restrict__ curB,
                        unsigned short* __restrict__ csr, int E, int half,
                        const float* __restrict__ x, unsigned short* __restrict__ xb,
                        int nx4, int bf) {
  const int b = blockIdx.x;
  if (b < bf) {
    int e = b * 256 + threadIdx.x;
    if (e < E) {
      int d = dst[e];
      int s = src[e];
      if (s < half) {
        int pos = atomicAdd(&curA[(size_t)d * CPAD], 1);
        csr[rowptr[d] + pos] = (unsigned short)s;
      } else {
        int pos = atomicAdd(&curB[(size_t)d * CPAD], 1);
        csr[rowptr[d + 1] - 1 - pos] = (unsigned short)s;
      }
    }
  } else {
    int i = (b - bf) * 256 + threadIdx.x;
    if (i < nx4) {
      // x is read exactly once -> non-temporal (protect L3 for xb/meanS/W)
      f32x4 v = __builtin_nontemporal_load(reinterpret_cast<const f32x4*>(x) + i);
      ushort4 o;
      o.x = f2bf_bits(v.x); o.y = f2bf_bits(v.y);
      o.z = f2bf_bits(v.z); o.w = f2bf_bits(v.w);
      reinterpret_cast<ushort4*>(xb)[i] = o;
    }
  }
}

// ---- bf16 accumulate helper ----
__device__ __forceinline__ void acc8(float* s, uint4 r) {
  const unsigned int u[4] = {r.x, r.y, r.z, r.w};
  #pragma unroll
  for (int k = 0; k < 4; ++k) {
    union { unsigned int u; float f; } lo, hi;
    lo.u = u[k] << 16;
    hi.u = u[k] & 0xffff0000u;
    s[2 * k]     += lo.f;
    s[2 * k + 1] += hi.f;
  }
}

// =====================================================================
// XCD channel-sliced aggregate (64-ch slices = full 128B lines).
// Slice s = channels [s*64,(s+1)*64), blocks with bid%8==s -> XCD s.
// Wave = 8 nodes x 8 lanes; accumulation LANE-LOCAL; 4-deep MLP (R15).
// =====================================================================
__global__ __launch_bounds__(256) void k_aggregate(
    const unsigned short* __restrict__ xb,
    const int* __restrict__ rowptr,
    const unsigned short* __restrict__ csr,
    unsigned short* __restrict__ meanS, int Nn) {
  const int s  = blockIdx.x & 7;                 // slice == XCD (bid%8)
  const int nb = blockIdx.x >> 3;                // node-block (32 nodes)
  const int wv = threadIdx.x >> 6;               // 4 waves/block
  const int lane = threadIdx.x & 63;
  const int g = lane >> 3, li = lane & 7;
  const int node = nb * 32 + wv * 8 + g;         // this group's node

  int beg = 0, deg = 0;
  if (node < Nn) {
    beg = rowptr[node];
    deg = rowptr[node + 1] - beg;
  }
  float acc[8] = {};
  const unsigned short* __restrict__ xs = xb + s * 64 + li * 8;

  int j = 0;
  for (; j + 4 <= deg; j += 4) {                 // 4 gathers in flight/group
    int i0 = (int)csr[beg + j];
    int i1 = (int)csr[beg + j + 1];
    int i2 = (int)csr[beg + j + 2];
    int i3 = (int)csr[beg + j + 3];
    uint4 r0 = *reinterpret_cast<const uint4*>(xs + (size_t)i0 * CI);
    uint4 r1 = *reinterpret_cast<const uint4*>(xs + (size_t)i1 * CI);
    uint4 r2 = *reinterpret_cast<const uint4*>(xs + (size_t)i2 * CI);
    uint4 r3 = *reinterpret_cast<const uint4*>(xs + (size_t)i3 * CI);
    acc8(acc, r0);
    acc8(acc, r1);
    acc8(acc, r2);
    acc8(acc, r3);
  }
  for (; j < deg; ++j) {
    int i0 = (int)csr[beg + j];
    uint4 r0 = *reinterpret_cast<const uint4*>(xs + (size_t)i0 * CI);
    acc8(acc, r0);
  }

  if (node < Nn) {
    const float inv = 1.f / fmaxf((float)deg, 1.f);
    unsigned short ob[8];
    #pragma unroll
    for (int k = 0; k < 8; ++k) ob[k] = f2bf_bits(acc[k] * inv);
    uint4 w;
    w.x = (unsigned int)ob[0] | ((unsigned int)ob[1] << 16);
    w.y = (unsigned int)ob[2] | ((unsigned int)ob[3] << 16);
    w.z = (unsigned int)ob[4] | ((unsigned int)ob[5] << 16);
    w.w = (unsigned int)ob[6] | ((unsigned int)ob[7] << 16);
    *reinterpret_cast<uint4*>(meanS + ((size_t)s * Nn + node) * 64 + li * 8) = w;
  }
}

// ---- bf16 MFMA GEMM v6: A-DIRECT (no LDS for A) ----
// A-fragments load straight to VGPRs (L3/L2-resident xb/meanS), double-
// buffered one tile ahead. LDS holds B only: 4 x 16KB ring in the same
// 64KB granule -> 2 B-tiles + 1 A-tile in flight across every barrier
// (vs 1 tile in the A+B-staged variants that all plateaued at ~86us).
#define BM 128
#define BN 128
#define BK 64
#define SLOT_SH 8192      // shorts per B slot (128 rows x 64 cols = 16KB)
#define EPAD 132          // f32 row pitch for epilogue LDS tile

#define WAITV(N) asm volatile("s_waitcnt vmcnt(" #N ")" ::: "memory")

__global__ __launch_bounds__(256) void k_gemm(
    const unsigned short* __restrict__ xb,
    const unsigned short* __restrict__ meanS,
    const unsigned short* __restrict__ Wb,
    const float* __restrict__ bias,
    float* __restrict__ out, int M) {
  __shared__ unsigned short lds[4 * SLOT_SH];   // 64 KB (B ring)
  const int tid = threadIdx.x;
  const int ntn = CO / BN;                       // 4

  // Bijective XCD-aware swizzle (m204; nwg=1564 not %8==0).
  const int nwg = gridDim.x;
  const int q = nwg >> 3, r = nwg & 7;
  const int xcd = blockIdx.x & 7, lid = blockIdx.x >> 3;
  const int wg = (xcd < r ? xcd * (q + 1) : r * (q + 1) + (xcd - r) * q) + lid;

  const int tm = wg / ntn, tn = wg % ntn;
  const int m0 = tm * BM, n0 = tn * BN;
  const int lane = tid & 63, wvid = tid >> 6;
  const int wm = wvid >> 1, wn = wvid & 1;       // 2M x 2N waves, 64x64 each
  const int lrow = lane & 15;
  const int lj4 = lane >> 4;                     // 0..3

  // B staging geometry (T2 chunk swizzle, unchanged): 128 rows x 64 cols,
  // 4 rounds x (256 thr x 16B). src chunk = stored-chunk ^ (row&7).
  int brow[4], bcol8[4];
  #pragma unroll
  for (int i = 0; i < 4; ++i) {
    int idx = i * 256 + tid;
    int rr = idx >> 3;
    brow[i] = rr;
    bcol8[i] = ((idx & 7) ^ (rr & 7)) * 8;
  }

  // A rows this lane reads (clamped)
  int garow[4];
  #pragma unroll
  for (int mi = 0; mi < 4; ++mi) {
    int g = m0 + wm * 64 + mi * 16 + lrow;
    garow[mi] = g < M ? g : M - 1;
  }

  const size_t Nn64 = (size_t)M * 64;

  f32x4 acc[4][4] = {};
  bf16x8 afbuf[2][8];                  // [t&1][kk*4+mi] — static-indexed

  // stage B K-tile kt into ring slot sl (4 global_load_lds per thread)
  auto stageB = [&](int kt, int sl) {
    unsigned short* sb = &lds[sl * SLOT_SH];
    const int kw = kt * 64;
    #pragma unroll
    for (int i = 0; i < 4; ++i)
      __builtin_amdgcn_global_load_lds(
        (const AS1 unsigned int*)(uintptr_t)(Wb + (size_t)(n0 + brow[i]) * (2 * CI) + kw + bcol8[i]),
        (AS3 unsigned int*)(uintptr_t)(&sb[(size_t)(i * 256 + tid) * 8]), 16, 0, 0);
  };

  // load A K-tile kt into register buffer (8 plain loads; compiler waits)
  auto loadA = [&](int kt, bf16x8* dst) {
    #pragma unroll
    for (int kk = 0; kk < 2; ++kk) {
      const int crd = kk * 4 + lj4;
      #pragma unroll
      for (int mi = 0; mi < 4; ++mi) {
        const unsigned short* p;
        if (kt < 8) p = xb + (size_t)garow[mi] * CI + kt * 64 + crd * 8;
        else        p = meanS + (size_t)(kt - 8) * Nn64 + (size_t)garow[mi] * 64 + crd * 8;
        dst[kk * 4 + mi] = *reinterpret_cast<const bf16x8*>(p);
      }
    }
  };

  auto compute = [&](int sl, const bf16x8* af) {
    const unsigned short* __restrict__ Lb = &lds[sl * SLOT_SH];
    #pragma unroll
    for (int kk = 0; kk < 2; ++kk) {
      const int crd = kk * 4 + lj4;
      bf16x8 bf[4];
      #pragma unroll
      for (int ni = 0; ni < 4; ++ni) {
        const int rb = wn * 64 + ni * 16 + lrow;
        bf[ni] = *reinterpret_cast<const bf16x8*>(&Lb[rb * BK + ((crd ^ (rb & 7)) * 8)]);
      }
      __builtin_amdgcn_s_setprio(1);
      #pragma unroll
      for (int mi = 0; mi < 4; ++mi)
        #pragma unroll
        for (int ni = 0; ni < 4; ++ni)
          acc[mi][ni] = __builtin_amdgcn_mfma_f32_16x16x32_bf16(af[kk * 4 + mi], bf[ni], acc[mi][ni], 0, 0, 0);
      __builtin_amdgcn_s_setprio(0);
    }
  };

  // prologue: 3 B-tiles staged, A(0) in regs
  stageB(0, 0);
  stageB(1, 1);
  stageB(2, 2);
  loadA(0, afbuf[0]);

  #pragma unroll
  for (int t = 0; t < 16; ++t) {
    if (t < 15) loadA(t + 1, afbuf[(t + 1) & 1]);   // A one tile ahead
    if (t < 13) stageB(t + 3, (t + 3) & 3);         // B three tiles ahead
    // Counted waits: ensure A(t) (and thus older B(t)) complete while
    // keeping B(t+2),A(t+1),B(t+3) in flight. Derived per-t:
    if (t == 0)       WAITV(12);
    else if (t < 13)  WAITV(16);
    else if (t == 13) WAITV(12);
    else if (t == 14) WAITV(8);
    else              WAITV(0);
    __builtin_amdgcn_s_barrier();      // all waves' B(t) writes visible
    __builtin_amdgcn_sched_barrier(0);
    compute(t & 3, afbuf[t & 1]);
    __builtin_amdgcn_sched_barrier(0);
    __builtin_amdgcn_s_barrier();      // slot t&3 free for stage(t+4)
  }

  // ---- LDS-staged epilogue, nt float4 stores (out never re-read) ----
  __syncthreads();
  float* lds_c = reinterpret_cast<float*>(&lds[0]);   // 16*EPAD*4 = 8448B
  const int lj = lane >> 4;
  float bv[4];
  #pragma unroll
  for (int ni = 0; ni < 4; ++ni) bv[ni] = bias[n0 + wn * 64 + ni * 16 + lrow];

  #pragma unroll
  for (int cw = 0; cw < 2; ++cw) {
    #pragma unroll
    for (int mi = 0; mi < 4; ++mi) {
      if (wm == cw) {
        #pragma unroll
        for (int ni = 0; ni < 4; ++ni)
          #pragma unroll
          for (int j = 0; j < 4; ++j)
            lds_c[(lj * 4 + j) * EPAD + wn * 64 + ni * 16 + lrow] = acc[mi][ni][j] + bv[ni];
      }
      __syncthreads();
      #pragma unroll
      for (int p = 0; p < 2; ++p) {
        int linear = p * 256 + tid;          // 0..511
        int rl = linear >> 5;                // 0..15
        int c4 = (linear & 31) << 2;         // 0..124
        int row = m0 + cw * 64 + mi * 16 + rl;
        if (row < M) {
          f32x4 v = *reinterpret_cast<const f32x4*>(&lds_c[rl * EPAD + c4]);
          __builtin_nontemporal_store(v,
            reinterpret_cast<f32x4*>(&out[(size_t)row * CO + n0 + c4]));
        }
      }
      __syncthreads();
    }
  }
}

extern "C" void kernel_launch(void* const* d_in, const int* in_sizes, int n_in,
                              void* d_out, int out_size, void* d_ws, size_t ws_size,
                              hipStream_t stream) {
  (void)n_in; (void)out_size; (void)ws_size;
  const float* x    = (const float*)d_in[0];
  const int*   ei   = (const int*)d_in[1];
  const float* W    = (const float*)d_in[2];
  const float* bias = (const float*)d_in[3];
  float* out = (float*)d_out;

  const int Nn = in_sizes[0] / CI;     // 50000
  const int E  = in_sizes[1] / 2;      // 800000
  const int* src = ei;
  const int* dst = ei + E;

  const int nblk = (Nn + 255) / 256;   // 196 scan blocks

  // workspace layout (~110 MB):
  int* cnt    = (int*)d_ws;                      // [Nn*CPAD]
  int* curA   = cnt + (size_t)Nn * CPAD;         // [Nn*CPAD]
  int* curB   = curA + (size_t)Nn * CPAD;        // [Nn*CPAD]
  int* rowptr = curB + (size_t)Nn * CPAD;        // [Nn+1]
  int* bsum   = rowptr + (Nn + 1);               // [nblk]
  uintptr_t p = (uintptr_t)(bsum + nblk);
  p = (p + 255) & ~(uintptr_t)255;
  unsigned short* csr = (unsigned short*)p;             // [E] u16 src ids
  p = (uintptr_t)(csr + E);
  p = (p + 255) & ~(uintptr_t)255;
  unsigned short* xb    = (unsigned short*)p;           // [Nn*CI] bf16
  unsigned short* meanS = xb + (size_t)Nn * CI;         // [8][Nn][64] bf16
  unsigned short* Wb    = meanS + (size_t)Nn * CI;      // [CO*2CI] bf16

  hipMemsetAsync(cnt, 0, (size_t)Nn * CPAD * sizeof(int), stream);  // cnt only

  const int nx4 = (Nn * CI) / 4;          // 6,400,000
  const int nw4 = (CO * 2 * CI) / 4;      // 131,072
  const int bx = (nx4 + 255) / 256;       // 25000 x-convert blocks
  const int bw = (nw4 + 255) / 256;       // 512 W-convert blocks
  const int be = (E + 255) / 256;         // 3125 edge blocks

  // stage 0: degree (first) + W convert — no dependencies
  k_prep0<<<be + bw, 256, 0, stream>>>(dst, cnt, E, W, Wb, nw4, be);
  k_bsum<<<nblk, 256, 0, stream>>>(cnt, bsum, Nn);
  k_scanf<<<nblk, 256, 0, stream>>>(cnt, bsum, rowptr, curA, curB, Nn, nblk);
  // CSR fill (first, latency-bound) + x convert (BW-bound) overlapped
  k_fillx<<<be + bx, 256, 0, stream>>>(src, dst, rowptr, curA, curB, csr, E, Nn / 2,
                                       x, xb, nx4, be);

  const int nab = ((Nn + 31) / 32) * 8;   // 1563 node-blocks x 8 slices
  k_aggregate<<<nab, 256, 0, stream>>>(xb, rowptr, csr, meanS, Nn);

  const int mtiles = (Nn + BM - 1) / BM;  // 391
  k_gemm<<<mtiles * (CO / BN), 256, 0, stream>>>(xb, meanS, Wb, bias, out, Nn);
}

// Round 19
// 245.975 us; speedup vs baseline: 1.2463x; 1.2463x over previous
//
#include <hip/hip_runtime.h>
#include <stdint.h>

// Problem constants (PureSAGEConv): N=50000, C_in=512, C_out=512, E=800000
#define CI 512
#define CO 512
#define CPAD 8   // counter padding stride (ints): 4 counters per 128B line

typedef __attribute__((ext_vector_type(4))) float f32x4;
typedef __attribute__((ext_vector_type(8))) __bf16 bf16x8;

#define AS1 __attribute__((address_space(1)))
#define AS3 __attribute__((address_space(3)))

__device__ __forceinline__ unsigned short f2bf_bits(float f) {
  union { float f; unsigned int u; } v; v.f = f;
  unsigned int u = v.u;
  unsigned int lsb = (u >> 16) & 1u;
  u += 0x7fffu + lsb;                 // round-to-nearest-even
  return (unsigned short)(u >> 16);
}

// ---- stage 0: degree histogram (blocks first) + W convert ----
__global__ void k_prep0(const int* __restrict__ dst, int* __restrict__ cnt, int E,
                        const float* __restrict__ W, unsigned short* __restrict__ Wb,
                        int nw4, int bd) {
  const int b = blockIdx.x;
  if (b < bd) {
    int e = b * 256 + threadIdx.x;
    if (e < E) atomicAdd(&cnt[dst[e] * CPAD], 1);
  } else {
    int i = (b - bd) * 256 + threadIdx.x;
    if (i < nw4) {
      float4 v = reinterpret_cast<const float4*>(W)[i];
      ushort4 o;
      o.x = f2bf_bits(v.x); o.y = f2bf_bits(v.y);
      o.z = f2bf_bits(v.z); o.w = f2bf_bits(v.w);
      reinterpret_cast<ushort4*>(Wb)[i] = o;
    }
  }
}

// ---- per-256-node block sums of (padded) degree counters ----
__global__ void k_bsum(const int* __restrict__ cnt, int* __restrict__ bsum, int n) {
  int t = threadIdx.x;
  int i = blockIdx.x * 256 + t;
  int v = (i < n) ? cnt[(size_t)i * CPAD] : 0;
  #pragma unroll
  for (int off = 32; off; off >>= 1) v += __shfl_down(v, off, 64);
  __shared__ int ws[4];
  if ((t & 63) == 0) ws[t >> 6] = v;
  __syncthreads();
  if (t == 0) bsum[blockIdx.x] = ws[0] + ws[1] + ws[2] + ws[3];
}

// ---- merged scan ----
__global__ void k_scanf(const int* __restrict__ cnt, const int* __restrict__ bsum,
                        int* __restrict__ rowptr, int n, int nb) {
  int t = threadIdx.x, lane = t & 63, w = t >> 6;
  __shared__ int ws1[4], ws2[4], sboff;

  int v0 = (t < nb) ? bsum[t] : 0;
  int s0 = v0;
  #pragma unroll
  for (int off = 1; off < 64; off <<= 1) {
    int u = __shfl_up(s0, off, 64);
    if (lane >= off) s0 += u;
  }
  if (lane == 63) ws1[w] = s0;
  __syncthreads();
  if (t == blockIdx.x) {
    int add0 = 0;
    for (int j = 0; j < w; ++j) add0 += ws1[j];
    sboff = s0 + add0 - v0;            // exclusive offset for this block
  }
  __syncthreads();

  int i = blockIdx.x * 256 + t;
  int v = (i < n) ? cnt[(size_t)i * CPAD] : 0;
  int s = v;
  #pragma unroll
  for (int off = 1; off < 64; off <<= 1) {
    int u = __shfl_up(s, off, 64);
    if (lane >= off) s += u;
  }
  if (lane == 63) ws2[w] = s;
  __syncthreads();
  int add = sboff;
  for (int j = 0; j < w; ++j) add += ws2[j];
  if (i < n) rowptr[i + 1] = s + add;
  if (i == 0) rowptr[0] = 0;
}

// ---- merged: CSR fill (latency-bound, blocks FIRST) + x->bf16 convert
// (BW-bound, floods in behind). ----
__global__ void k_fillx(const int* __restrict__ src, const int* __restrict__ dst,
                        const int* __restrict__ rowptr,
                        int* __restrict__ curA, int* __restrict__ curB,
                        unsigned short* __restrict__ csr, int E, int half,
                        const float* __restrict__ x, unsigned short* __restrict__ xb,
                        int nx4, int bf) {
  const int b = blockIdx.x;
  if (b < bf) {
    int e = b * 256 + threadIdx.x;
    if (e < E) {
      int d = dst[e];
      int s = src[e];
      if (s < half) {
        int pos = atomicAdd(&curA[(size_t)d * CPAD], 1);
        csr[rowptr[d] + pos] = (unsigned short)s;
      } else {
        int pos = atomicAdd(&curB[(size_t)d * CPAD], 1);
        csr[rowptr[d + 1] - 1 - pos] = (unsigned short)s;
      }
    }
  } else {
    int i = (b - bf) * 256 + threadIdx.x;
    if (i < nx4) {
      // x is read exactly once -> non-temporal (protect L3 for xb/meanS/W)
      f32x4 v = __builtin_nontemporal_load(reinterpret_cast<const f32x4*>(x) + i);
      ushort4 o;
      o.x = f2bf_bits(v.x); o.y = f2bf_bits(v.y);
      o.z = f2bf_bits(v.z); o.w = f2bf_bits(v.w);
      reinterpret_cast<ushort4*>(xb)[i] = o;
    }
  }
}

// ---- bf16 accumulate helper ----
__device__ __forceinline__ void acc8(float* s, uint4 r) {
  const unsigned int u[4] = {r.x, r.y, r.z, r.w};
  #pragma unroll
  for (int k = 0; k < 4; ++k) {
    union { unsigned int u; float f; } lo, hi;
    lo.u = u[k] << 16;
    hi.u = u[k] & 0xffff0000u;
    s[2 * k]     += lo.f;
    s[2 * k + 1] += hi.f;
  }
}

// =====================================================================
// XCD channel-sliced aggregate (64-ch slices = full 128B lines).
// Slice s = channels [s*64,(s+1)*64), blocks with bid%8==s -> XCD s.
// Wave = 8 nodes x 8 lanes; accumulation LANE-LOCAL.
// 4 gathers in flight per group (R15 best; 8-deep measured no better).
// =====================================================================
__global__ __launch_bounds__(256) void k_aggregate(
    const unsigned short* __restrict__ xb,
    const int* __restrict__ rowptr,
    const unsigned short* __restrict__ csr,
    unsigned short* __restrict__ meanS, int Nn) {
  const int s  = blockIdx.x & 7;                 // slice == XCD (bid%8)
  const int nb = blockIdx.x >> 3;                // node-block (32 nodes)
  const int wv = threadIdx.x >> 6;               // 4 waves/block
  const int lane = threadIdx.x & 63;
  const int g = lane >> 3, li = lane & 7;
  const int node = nb * 32 + wv * 8 + g;         // this group's node

  int beg = 0, deg = 0;
  if (node < Nn) {
    beg = rowptr[node];
    deg = rowptr[node + 1] - beg;
  }
  float acc[8] = {};
  const unsigned short* __restrict__ xs = xb + s * 64 + li * 8;

  int j = 0;
  for (; j + 4 <= deg; j += 4) {                 // 4 gathers in flight/group
    int i0 = (int)csr[beg + j];
    int i1 = (int)csr[beg + j + 1];
    int i2 = (int)csr[beg + j + 2];
    int i3 = (int)csr[beg + j + 3];
    uint4 r0 = *reinterpret_cast<const uint4*>(xs + (size_t)i0 * CI);
    uint4 r1 = *reinterpret_cast<const uint4*>(xs + (size_t)i1 * CI);
    uint4 r2 = *reinterpret_cast<const uint4*>(xs + (size_t)i2 * CI);
    uint4 r3 = *reinterpret_cast<const uint4*>(xs + (size_t)i3 * CI);
    acc8(acc, r0);
    acc8(acc, r1);
    acc8(acc, r2);
    acc8(acc, r3);
  }
  for (; j < deg; ++j) {
    int i0 = (int)csr[beg + j];
    uint4 r0 = *reinterpret_cast<const uint4*>(xs + (size_t)i0 * CI);
    acc8(acc, r0);
  }

  if (node < Nn) {
    const float inv = 1.f / fmaxf((float)deg, 1.f);
    unsigned short ob[8];
    #pragma unroll
    for (int k = 0; k < 8; ++k) ob[k] = f2bf_bits(acc[k] * inv);
    uint4 w;
    w.x = (unsigned int)ob[0] | ((unsigned int)ob[1] << 16);
    w.y = (unsigned int)ob[2] | ((unsigned int)ob[3] << 16);
    w.z = (unsigned int)ob[4] | ((unsigned int)ob[5] << 16);
    w.w = (unsigned int)ob[6] | ((unsigned int)ob[7] << 16);
    *reinterpret_cast<uint4*>(meanS + ((size_t)s * Nn + node) * 64 + li * 8) = w;
  }
}

// ---- bf16 MFMA GEMM (R11 exact): BM=128 BN=128 BK=64, 2 blocks/CU,
// double-buffered 64KB LDS, counted WAITV(8); nt stores for out. ----
#define BM 128
#define BN 128
#define BK 64
#define SLOT_SH 16384     // shorts per slot: A 8192 (16KB) + B 8192 (16KB)
#define BOFF 8192         // B base within slot (shorts)
#define EPAD 132          // f32 row pitch for epilogue LDS tile

#define WAITV(N) asm volatile("s_waitcnt vmcnt(" #N ")" ::: "memory")

__global__ __launch_bounds__(256) void k_gemm(
    const unsigned short* __restrict__ xb,
    const unsigned short* __restrict__ meanS,
    const unsigned short* __restrict__ Wb,
    const float* __restrict__ bias,
    float* __restrict__ out, int M) {
  __shared__ unsigned short lds[2 * SLOT_SH];   // 64 KB
  const int tid = threadIdx.x;
  const int ntn = CO / BN;                       // 4

  // Bijective XCD-aware swizzle (m204; nwg=1564 not %8==0).
  const int nwg = gridDim.x;
  const int q = nwg >> 3, r = nwg & 7;
  const int xcd = blockIdx.x & 7, lid = blockIdx.x >> 3;
  const int wg = (xcd < r ? xcd * (q + 1) : r * (q + 1) + (xcd - r) * q) + lid;

  const int tm = wg / ntn, tn = wg % ntn;
  const int m0 = tm * BM, n0 = tn * BN;
  const int lane = tid & 63, wvid = tid >> 6;
  const int wm = wvid >> 1, wn = wvid & 1;       // 2M x 2N waves, 64x64 each
  const int lrow = lane & 15;

  // staging geometry (T2 chunk swizzle): 128 rows x 64 cols per operand,
  // 4 rounds x (256 thr x 16B). src chunk = stored-chunk ^ (row&7).
  int arow[4], gra[4], scol8[4];
  #pragma unroll
  for (int i = 0; i < 4; ++i) {
    int idx = i * 256 + tid;
    int rr = idx >> 3;
    arow[i] = rr;
    scol8[i] = ((idx & 7) ^ (rr & 7)) * 8;
    int g = m0 + rr;
    gra[i] = g < M ? g : M - 1;
  }

  const size_t Nn64 = (size_t)M * 64;

  f32x4 acc[4][4] = {};

  // stage K-tile kt into slot sl (8 global_load_lds per thread)
  auto stage = [&](int kt, int sl) {
    unsigned short* sa = &lds[sl * SLOT_SH];
    unsigned short* sb = sa + BOFF;
    if (kt < 8) {
      const int ka = kt * 64;
      #pragma unroll
      for (int i = 0; i < 4; ++i)
        __builtin_amdgcn_global_load_lds(
          (const AS1 unsigned int*)(uintptr_t)(xb + (size_t)gra[i] * CI + ka + scol8[i]),
          (AS3 unsigned int*)(uintptr_t)(&sa[(size_t)(i * 256 + tid) * 8]), 16, 0, 0);
    } else {
      const unsigned short* __restrict__ A = meanS + (size_t)(kt - 8) * Nn64;
      #pragma unroll
      for (int i = 0; i < 4; ++i)
        __builtin_amdgcn_global_load_lds(
          (const AS1 unsigned int*)(uintptr_t)(A + (size_t)gra[i] * 64 + scol8[i]),
          (AS3 unsigned int*)(uintptr_t)(&sa[(size_t)(i * 256 + tid) * 8]), 16, 0, 0);
    }
    const int kw = kt * 64;
    #pragma unroll
    for (int i = 0; i < 4; ++i)
      __builtin_amdgcn_global_load_lds(
        (const AS1 unsigned int*)(uintptr_t)(Wb + (size_t)(n0 + arow[i]) * (2 * CI) + kw + scol8[i]),
        (AS3 unsigned int*)(uintptr_t)(&sb[(size_t)(i * 256 + tid) * 8]), 16, 0, 0);
  };

  auto compute = [&](int sl) {
    const unsigned short* __restrict__ La = &lds[sl * SLOT_SH];
    const unsigned short* __restrict__ Lb = La + BOFF;
    #pragma unroll
    for (int kk = 0; kk < 2; ++kk) {
      const int crd = kk * 4 + (lane >> 4);
      bf16x8 af[4], bf[4];
      #pragma unroll
      for (int mi = 0; mi < 4; ++mi) {
        const int rr = wm * 64 + mi * 16 + lrow;
        af[mi] = *reinterpret_cast<const bf16x8*>(&La[rr * BK + ((crd ^ (rr & 7)) * 8)]);
      }
      #pragma unroll
      for (int ni = 0; ni < 4; ++ni) {
        const int rb = wn * 64 + ni * 16 + lrow;
        bf[ni] = *reinterpret_cast<const bf16x8*>(&Lb[rb * BK + ((crd ^ (rb & 7)) * 8)]);
      }
      __builtin_amdgcn_s_setprio(1);
      #pragma unroll
      for (int mi = 0; mi < 4; ++mi)
        #pragma unroll
        for (int ni = 0; ni < 4; ++ni)
          acc[mi][ni] = __builtin_amdgcn_mfma_f32_16x16x32_bf16(af[mi], bf[ni], acc[mi][ni], 0, 0, 0);
      __builtin_amdgcn_s_setprio(0);
    }
  };

  stage(0, 0);                         // prologue: 1 tile in flight

  #pragma unroll
  for (int t = 0; t < 16; ++t) {
    if (t < 15) {
      stage(t + 1, (t + 1) & 1);       // fill the other buffer
      WAITV(8);                        // tile t's 8 loads done; t+1's in flight
    } else {
      WAITV(0);
    }
    __builtin_amdgcn_s_barrier();      // tile t ready for ALL waves
    __builtin_amdgcn_sched_barrier(0);
    compute(t & 1);
    __builtin_amdgcn_sched_barrier(0);
    __builtin_amdgcn_s_barrier();      // all waves done reading slot t&1
  }

  // ---- LDS-staged epilogue, nt float4 stores (out never re-read) ----
  __syncthreads();
  float* lds_c = reinterpret_cast<float*>(&lds[0]);   // 16*EPAD*4 = 8448B
  const int lj = lane >> 4;
  float bv[4];
  #pragma unroll
  for (int ni = 0; ni < 4; ++ni) bv[ni] = bias[n0 + wn * 64 + ni * 16 + lrow];

  #pragma unroll
  for (int cw = 0; cw < 2; ++cw) {
    #pragma unroll
    for (int mi = 0; mi < 4; ++mi) {
      if (wm == cw) {
        #pragma unroll
        for (int ni = 0; ni < 4; ++ni)
          #pragma unroll
          for (int j = 0; j < 4; ++j)
            lds_c[(lj * 4 + j) * EPAD + wn * 64 + ni * 16 + lrow] = acc[mi][ni][j] + bv[ni];
      }
      __syncthreads();
      #pragma unroll
      for (int p = 0; p < 2; ++p) {
        int linear = p * 256 + tid;          // 0..511
        int rl = linear >> 5;                // 0..15
        int c4 = (linear & 31) << 2;         // 0..124
        int row = m0 + cw * 64 + mi * 16 + rl;
        if (row < M) {
          f32x4 v = *reinterpret_cast<const f32x4*>(&lds_c[rl * EPAD + c4]);
          __builtin_nontemporal_store(v,
            reinterpret_cast<f32x4*>(&out[(size_t)row * CO + n0 + c4]));
        }
      }
      __syncthreads();
    }
  }
}

extern "C" void kernel_launch(void* const* d_in, const int* in_sizes, int n_in,
                              void* d_out, int out_size, void* d_ws, size_t ws_size,
                              hipStream_t stream) {
  (void)n_in; (void)out_size; (void)ws_size;
  const float* x    = (const float*)d_in[0];
  const int*   ei   = (const int*)d_in[1];
  const float* W    = (const float*)d_in[2];
  const float* bias = (const float*)d_in[3];
  float* out = (float*)d_out;

  const int Nn = in_sizes[0] / CI;     // 50000
  const int E  = in_sizes[1] / 2;      // 800000
  const int* src = ei;
  const int* dst = ei + E;

  const int nblk = (Nn + 255) / 256;   // 196 scan blocks

  // workspace layout (~110 MB):
  int* cnt    = (int*)d_ws;                      // [Nn*CPAD]
  int* curA   = cnt + (size_t)Nn * CPAD;         // [Nn*CPAD]
  int* curB   = curA + (size_t)Nn * CPAD;        // [Nn*CPAD]
  int* rowptr = curB + (size_t)Nn * CPAD;        // [Nn+1]
  int* bsum   = rowptr + (Nn + 1);               // [nblk]
  uintptr_t p = (uintptr_t)(bsum + nblk);
  p = (p + 255) & ~(uintptr_t)255;
  unsigned short* csr = (unsigned short*)p;             // [E] u16 src ids
  p = (uintptr_t)(csr + E);
  p = (p + 255) & ~(uintptr_t)255;
  unsigned short* xb    = (unsigned short*)p;           // [Nn*CI] bf16
  unsigned short* meanS = xb + (size_t)Nn * CI;         // [8][Nn][64] bf16
  unsigned short* Wb    = meanS + (size_t)Nn * CI;      // [CO*2CI] bf16

  hipMemsetAsync(cnt, 0, (size_t)3 * Nn * CPAD * sizeof(int), stream);  // cnt+curA+curB

  const int nx4 = (Nn * CI) / 4;          // 6,400,000
  const int nw4 = (CO * 2 * CI) / 4;      // 131,072
  const int bx = (nx4 + 255) / 256;       // 25000 x-convert blocks
  const int bw = (nw4 + 255) / 256;       // 512 W-convert blocks
  const int be = (E + 255) / 256;         // 3125 edge blocks

  // stage 0: degree (first) + W convert — no dependencies
  k_prep0<<<be + bw, 256, 0, stream>>>(dst, cnt, E, W, Wb, nw4, be);
  k_bsum<<<nblk, 256, 0, stream>>>(cnt, bsum, Nn);
  k_scanf<<<nblk, 256, 0, stream>>>(cnt, bsum, rowptr, Nn, nblk);
  // CSR fill (first, latency-bound) + x convert (BW-bound) overlapped
  k_fillx<<<be + bx, 256, 0, stream>>>(src, dst, rowptr, curA, curB, csr, E, Nn / 2,
                                       x, xb, nx4, be);

  const int nab = ((Nn + 31) / 32) * 8;   // 1563 node-blocks x 8 slices
  k_aggregate<<<nab, 256, 0, stream>>>(xb, rowptr, csr, meanS, Nn);

  const int mtiles = (Nn + BM - 1) / BM;  // 391
  k_gemm<<<mtiles * (CO / BN), 256, 0, stream>>>(xb, meanS, Wb, bias, out, Nn);
}